// Round 5
// baseline (639.874 us; speedup 1.0000x reference)
//
#include <hip/hip_runtime.h>

#define SCALE_LORA 2.0f
// GEMM: 256x256 tile, BK=32, 8 waves (2M x 4N), NBUF=4 ring, free-run interior:
// ONE barrier + ONE counted vmcnt per K-tile; R/M clusters fenced for dual-issue.
#define BM 256
#define BN 256
#define BK 32

#define AS1 __attribute__((address_space(1)))
#define AS3 __attribute__((address_space(3)))

using bf16x8 = __attribute__((ext_vector_type(8))) __bf16;
using f32x4  = __attribute__((ext_vector_type(4))) float;
using u16x8  = __attribute__((ext_vector_type(8))) unsigned short;

#define MFMA(a, b, c) __builtin_amdgcn_mfma_f32_16x16x32_bf16((a), (b), (c), 0, 0, 0)

static __device__ __forceinline__ unsigned short f2bf_rne(float f) {
  unsigned int u = __builtin_bit_cast(unsigned int, f);
  u += 0x7FFFu + ((u >> 16) & 1u);   // round-to-nearest-even
  return (unsigned short)(u >> 16);
}

// ---------- kernel 1: x f32 -> bf16 (vectorized, grid-stride) ----------
__global__ void cvt_bf16_kernel(const float* __restrict__ x,
                                unsigned short* __restrict__ xb, long n) {
  long stride = (long)gridDim.x * blockDim.x;
  long nv = n >> 3;
  for (long i = (long)blockIdx.x * blockDim.x + threadIdx.x; i < nv; i += stride) {
    long base = i << 3;
    f32x4 a = *(const f32x4*)(x + base);
    f32x4 b = *(const f32x4*)(x + base + 4);
    u16x8 o;
    o[0] = f2bf_rne(a[0]); o[1] = f2bf_rne(a[1]);
    o[2] = f2bf_rne(a[2]); o[3] = f2bf_rne(a[3]);
    o[4] = f2bf_rne(b[0]); o[5] = f2bf_rne(b[1]);
    o[6] = f2bf_rne(b[2]); o[7] = f2bf_rne(b[3]);
    *(u16x8*)(xb + base) = o;
  }
}

// ---------- kernel 2: W_eff^T = (W + 2*A@B)^T as bf16, N x K ----------
__global__ void build_wt_kernel(const float* __restrict__ W,
                                const float* __restrict__ A,
                                const float* __restrict__ Bmat,
                                unsigned short* __restrict__ WT,
                                int K, int N, int R) {
  __shared__ float Bs[16][64];
  __shared__ unsigned short Tt[64][66];
  int ntn = N >> 6;
  int kt = blockIdx.x / ntn, nt = blockIdx.x - kt * ntn;
  int k0 = kt << 6, n0 = nt << 6;
  int t = threadIdx.x;
  int tx = t & 63, ty = t >> 6;

  for (int i = t; i < R * 64; i += 256)
    Bs[i >> 6][i & 63] = Bmat[(long)(i >> 6) * N + n0 + (i & 63)];
  __syncthreads();

  for (int it = 0; it < 16; ++it) {
    int kl = (it << 2) + ty;
    long kg = k0 + kl;
    float w = W[kg * N + n0 + tx];
    const float* Ar = A + kg * R;
    float s = 0.f;
    for (int r = 0; r < R; ++r) s += Ar[r] * Bs[r][tx];
    Tt[kl][tx] = f2bf_rne(w + SCALE_LORA * s);
  }
  __syncthreads();

  for (int it = 0; it < 16; ++it) {
    int nn = (it << 2) + ty;
    WT[(long)(n0 + nn) * K + k0 + tx] = Tt[tx][nn];
  }
}

// ---------- kernel 3: free-run-interior deep-pipelined GEMM ----------
// Rows are 64 B -> swizzle: granule ^= (row>>1)&3 (verified 0-conflict, r3),
// applied as inverse-swizzled GLOBAL SOURCE (linear gload_lds dest) +
// swizzled ds_read addr (involution, both-sides rule).
__global__ __launch_bounds__(512, 2) void gemm_kernel(
    const unsigned short* __restrict__ Xb,  // M x K bf16
    const unsigned short* __restrict__ WT,  // N x K bf16 (pre-transposed)
    const float* __restrict__ bias,         // N f32
    float* __restrict__ out,                // M x N f32
    int M, int N, int K)
{
  extern __shared__ unsigned short lds[];   // 128 KiB
  // A bufs: elems b*8192, b=0..3 (16 KB each); B bufs: 32768 + b*8192

  int nwg = gridDim.x;
  int bid = blockIdx.x;
  if ((nwg & 7) == 0) {
    int cpx = nwg >> 3;
    bid = (bid & 7) * cpx + (bid >> 3);
  }
  int ntn = N / BN;
  int tm = bid / ntn;
  int tn = bid - tm * ntn;
  const long m0 = (long)tm * BM;
  const long n0 = (long)tn * BN;

  int tid  = threadIdx.x;
  int lane = tid & 63;
  int wave = tid >> 6;
  int wr = wave >> 2;        // 0..1 : 128-row half (M)
  int wc = wave & 3;         // 0..3 : 64-col quarter (N)
  int l15 = lane & 15;
  int g   = lane >> 4;

  f32x4 acc[8][4] = {};

  // staging: thread t covers row = t>>2, LDS granule slot t&3 holds
  // source granule (t&3) ^ ((row>>1)&3) = (t&3) ^ ((t>>3)&3)
  int srccol = 8 * ((tid & 3) ^ ((tid >> 3) & 3));
  const unsigned short* aSrc = Xb + (m0 + (tid >> 2)) * (long)K + srccol;
  const unsigned short* bSrc = WT + (n0 + (tid >> 2)) * (long)K + srccol;
  const int ldsByte = tid * 16;

  // fragment read bases (elems), swizzled granule = g ^ ((row>>1)&3)
  const int swzg = g ^ ((l15 >> 1) & 3);
  const int fragA = (wr * 128 + l15) * BK + 8 * swzg;   // + m*512
  const int fragB = (wc * 64  + l15) * BK + 8 * swzg;   // + n*512

  const int nt = K / BK;   // 128

#define STAGEA(buf, kt) do { long ko_ = (long)(kt) * BK;                     \
    _Pragma("unroll")                                                        \
    for (int j_ = 0; j_ < 2; ++j_)                                           \
      __builtin_amdgcn_global_load_lds(                                      \
        (const AS1 void*)(aSrc + j_*128*(long)K + ko_),                      \
        (AS3 void*)((char*)lds + (buf)*16384 + j_*8192 + ldsByte), 16,0,0);  \
  } while (0)

#define STAGEB(buf, kt) do { long ko_ = (long)(kt) * BK;                     \
    _Pragma("unroll")                                                        \
    for (int j_ = 0; j_ < 2; ++j_)                                           \
      __builtin_amdgcn_global_load_lds(                                      \
        (const AS1 void*)(bSrc + j_*128*(long)K + ko_),                      \
        (AS3 void*)((char*)lds + 65536 + (buf)*16384 + j_*8192 + ldsByte),   \
        16,0,0);                                                             \
  } while (0)

#define SBAR  __builtin_amdgcn_sched_barrier(0)

  // One K-tile, free-run interior (single barrier at top):
  //   R1(8 ds_read)+STA | R2(4 ds_read)+STB | M1(16 MFMA, lgkm(4) auto,
  //   R2 in flight under it) | M2(16 MFMA, lgkm(0))
#define TILE(BUFI, VMSTR, STA, STB) do {                                     \
    asm volatile("s_waitcnt vmcnt(" VMSTR ")" ::: "memory");                 \
    __builtin_amdgcn_s_barrier();                                            \
    SBAR;                                                                    \
    const unsigned short* Ab_ = lds + (BUFI)*8192 + fragA;                   \
    const unsigned short* Bb_ = lds + 32768 + (BUFI)*8192 + fragB;           \
    bf16x8 af_[8], bf_[4];                                                   \
    _Pragma("unroll")                                                        \
    for (int m_ = 0; m_ < 4; ++m_) af_[m_] = *(const bf16x8*)(Ab_ + m_*512); \
    _Pragma("unroll")                                                        \
    for (int n_ = 0; n_ < 4; ++n_) bf_[n_] = *(const bf16x8*)(Bb_ + n_*512); \
    STA;                                                                     \
    SBAR;                                                                    \
    _Pragma("unroll")                                                        \
    for (int m_ = 0; m_ < 4; ++m_) af_[m_+4] = *(const bf16x8*)(Ab_ + (m_+4)*512); \
    STB;                                                                     \
    SBAR;                                                                    \
    __builtin_amdgcn_s_setprio(1);                                           \
    _Pragma("unroll")                                                        \
    for (int m_ = 0; m_ < 4; ++m_)                                           \
      _Pragma("unroll")                                                      \
      for (int n_ = 0; n_ < 4; ++n_)                                         \
        acc[m_][n_] = MFMA(af_[m_], bf_[n_], acc[m_][n_]);                   \
    __builtin_amdgcn_s_setprio(0);                                           \
    SBAR;                                                                    \
    __builtin_amdgcn_s_setprio(1);                                           \
    _Pragma("unroll")                                                        \
    for (int m_ = 0; m_ < 4; ++m_)                                           \
      _Pragma("unroll")                                                      \
      for (int n_ = 0; n_ < 4; ++n_)                                         \
        acc[m_+4][n_] = MFMA(af_[m_+4], bf_[n_], acc[m_+4][n_]);             \
    __builtin_amdgcn_s_setprio(0);                                           \
    SBAR;                                                                    \
  } while (0)

  // prologue: 3 K-tiles staged (12 loads in flight)
  STAGEA(0, 0); STAGEB(0, 0);
  STAGEA(1, 1); STAGEB(1, 1);
  STAGEA(2, 2); STAGEB(2, 2);

  // steady state: read buf t&3; stage t+3 into buf (t+3)&3 = (t-1)&3, which
  // is free: all waves' t-1 reads completed before tile t's top barrier.
  for (int t = 0; t < nt - 3; ++t) {
    TILE(t & 3, "8", STAGEA((t + 3) & 3, t + 3), STAGEB((t + 3) & 3, t + 3));
  }
  TILE((nt - 3) & 3, "8", , );
  TILE((nt - 2) & 3, "4", , );
  TILE((nt - 1) & 3, "0", , );

#undef TILE
#undef STAGEA
#undef STAGEB

  // epilogue: C/D layout col = lane&15, row = (lane>>4)*4 + i
  #pragma unroll
  for (int n = 0; n < 4; ++n) {
    long col = n0 + wc * 64 + n * 16 + l15;
    float bv = bias[col];
    #pragma unroll
    for (int m = 0; m < 8; ++m) {
      long row0 = m0 + wr * 128 + m * 16 + (g << 2);
      #pragma unroll
      for (int i = 0; i < 4; ++i)
        out[(row0 + i) * (long)N + col] = acc[m][n][i] + bv;
    }
  }
}

extern "C" void kernel_launch(void* const* d_in, const int* in_sizes, int n_in,
                              void* d_out, int out_size, void* d_ws, size_t ws_size,
                              hipStream_t stream) {
  const float* x    = (const float*)d_in[0];
  const float* W    = (const float*)d_in[1];
  const float* b    = (const float*)d_in[2];
  const float* A    = (const float*)d_in[3];
  const float* Bm   = (const float*)d_in[4];

  const long D_out = in_sizes[2];                 // 4096
  const long D_in  = (long)in_sizes[1] / D_out;   // 4096
  const long M     = (long)in_sizes[0] / D_in;    // 16384
  const int  R     = (int)((long)in_sizes[3] / D_in);  // 16
  const int  K = (int)D_in, N = (int)D_out;

  unsigned short* xb = (unsigned short*)d_ws;
  unsigned short* wt = xb + (size_t)M * K;

  cvt_bf16_kernel<<<2048, 256, 0, stream>>>(x, xb, M * (long)K);
  build_wt_kernel<<<(K >> 6) * (N >> 6), 256, 0, stream>>>(W, A, Bm, wt, K, N, R);

  int grid = (int)((M / BM) * ((long)N / BN));    // 64 * 16 = 1024
  gemm_kernel<<<grid, 512, 128 * 1024, stream>>>(
      xb, wt, b, (float*)d_out, (int)M, N, K);
}

// Round 7
// 612.556 us; speedup vs baseline: 1.0446x; 1.0446x over previous
//
#include <hip/hip_runtime.h>

#define SCALE_LORA 2.0f
// GEMM: 256x256 tile, BK=64, 8 waves (2M x 4N), 2-K-tile/iter, 8 phases,
// per-phase half-tile staging, vmcnt(4)@ph1/ph5 + BARRIER AFTER VMCNT (r6 fix)
#define BM 256
#define BN 256
#define BK 64

#define AS1 __attribute__((address_space(1)))
#define AS3 __attribute__((address_space(3)))

using bf16x8 = __attribute__((ext_vector_type(8))) __bf16;
using f32x4  = __attribute__((ext_vector_type(4))) float;
using u16x8  = __attribute__((ext_vector_type(8))) unsigned short;

#define MFMA(a, b, c) __builtin_amdgcn_mfma_f32_16x16x32_bf16((a), (b), (c), 0, 0, 0)

static __device__ __forceinline__ unsigned short f2bf_rne(float f) {
  unsigned int u = __builtin_bit_cast(unsigned int, f);
  u += 0x7FFFu + ((u >> 16) & 1u);   // round-to-nearest-even
  return (unsigned short)(u >> 16);
}

// ---------- kernel 1: x f32 -> bf16 (vectorized, grid-stride) ----------
__global__ void cvt_bf16_kernel(const float* __restrict__ x,
                                unsigned short* __restrict__ xb, long n) {
  long stride = (long)gridDim.x * blockDim.x;
  long nv = n >> 3;
  for (long i = (long)blockIdx.x * blockDim.x + threadIdx.x; i < nv; i += stride) {
    long base = i << 3;
    f32x4 a = *(const f32x4*)(x + base);
    f32x4 b = *(const f32x4*)(x + base + 4);
    u16x8 o;
    o[0] = f2bf_rne(a[0]); o[1] = f2bf_rne(a[1]);
    o[2] = f2bf_rne(a[2]); o[3] = f2bf_rne(a[3]);
    o[4] = f2bf_rne(b[0]); o[5] = f2bf_rne(b[1]);
    o[6] = f2bf_rne(b[2]); o[7] = f2bf_rne(b[3]);
    *(u16x8*)(xb + base) = o;
  }
}

// ---------- kernel 2: W_eff^T = (W + 2*A@B)^T as bf16, N x K ----------
__global__ void build_wt_kernel(const float* __restrict__ W,
                                const float* __restrict__ A,
                                const float* __restrict__ Bmat,
                                unsigned short* __restrict__ WT,
                                int K, int N, int R) {
  __shared__ float Bs[16][64];
  __shared__ unsigned short Tt[64][66];
  int ntn = N >> 6;
  int kt = blockIdx.x / ntn, nt = blockIdx.x - kt * ntn;
  int k0 = kt << 6, n0 = nt << 6;
  int t = threadIdx.x;
  int tx = t & 63, ty = t >> 6;

  for (int i = t; i < R * 64; i += 256)
    Bs[i >> 6][i & 63] = Bmat[(long)(i >> 6) * N + n0 + (i & 63)];
  __syncthreads();

  for (int it = 0; it < 16; ++it) {
    int kl = (it << 2) + ty;
    long kg = k0 + kl;
    float w = W[kg * N + n0 + tx];
    const float* Ar = A + kg * R;
    float s = 0.f;
    for (int r = 0; r < R; ++r) s += Ar[r] * Bs[r][tx];
    Tt[kl][tx] = f2bf_rne(w + SCALE_LORA * s);
  }
  __syncthreads();

  for (int it = 0; it < 16; ++it) {
    int nn = (it << 2) + ty;
    WT[(long)(n0 + nn) * K + k0 + tx] = Tt[tx][nn];
  }
}

// ---------- kernel 3: m201-faithful 8-phase GEMM (sync-fixed) ----------
// Rows are 128 B -> swizzle granule = ((kh<<2)|g) ^ (row&7): low 2 bits via
// read-addr XOR, bit2 via per-lane k-half swap (kx0/kx1). Verified 0-conflict
// (r4). Applied as inverse-swizzled GLOBAL SOURCE + swizzled ds_read.
__global__ __launch_bounds__(512, 2) void gemm_kernel(
    const unsigned short* __restrict__ Xb,  // M x K bf16
    const unsigned short* __restrict__ WT,  // N x K bf16 (pre-transposed)
    const float* __restrict__ bias,         // N f32
    float* __restrict__ out,                // M x N f32
    int M, int N, int K)
{
  extern __shared__ unsigned short lds[];   // 128 KiB
  // A: bytes [0,65536) = 2 bufs x 32768; B: [65536,131072). Half h of buf b
  // at matrix_base + b*32768 + h*16384 (bytes).

  int nwg = gridDim.x;
  int bid = blockIdx.x;
  if ((nwg & 7) == 0) {
    int cpx = nwg >> 3;
    bid = (bid & 7) * cpx + (bid >> 3);
  }
  int ntn = N / BN;
  int tm = bid / ntn;
  int tn = bid - tm * ntn;
  const long m0 = (long)tm * BM;
  const long n0 = (long)tn * BN;

  int tid  = threadIdx.x;
  int lane = tid & 63;
  int wave = tid >> 6;
  int wr = wave >> 2;        // 0..1 : 128-row half (M)
  int wc = wave & 3;         // 0..3 : 64-col quarter (N)
  int l15 = lane & 15;
  int g   = lane >> 4;

  f32x4 acc[8][4] = {};

  // staging: thread t covers row = t>>3, source granule (t&7)^((t>>3)&7)
  int srccol = 8 * ((tid & 7) ^ ((tid >> 3) & 7));
  const unsigned short* aSrc = Xb + (m0 + (tid >> 3)) * (long)K + srccol;
  const unsigned short* bSrc = WT + (n0 + (tid >> 3)) * (long)K + srccol;
  const int ldsByte = tid * 16;

  // fragment read bases (elems): low-2-bit swizzle in addr, bit2 via kx swap
  const int fragA = (wr * 128 + l15) * 64 + 8 * (g ^ (l15 & 3));
  const int fragB = (wc * 64  + l15) * 64 + 8 * (g ^ (l15 & 3));
  const int kx0 = ((l15 >> 2) & 1) << 5;   // 0 or 32 elems
  const int kx1 = kx0 ^ 32;

  const int nt = K / BK;   // 64 K-tiles; 32 pair-iterations

  // stage one half-tile (2 x global_load_lds)
#define STGA(b, h, kt) do {                                                  \
    _Pragma("unroll")                                                        \
    for (int j_ = 0; j_ < 2; ++j_)                                           \
      __builtin_amdgcn_global_load_lds(                                      \
        (const AS1 void*)(aSrc + ((h)*128 + j_*64)*(long)K + (long)(kt)*BK), \
        (AS3 void*)((char*)lds + (b)*32768 + (h)*16384 + j_*8192 + ldsByte), \
        16,0,0);                                                             \
  } while (0)
#define STGB(b, h, kt) do {                                                  \
    _Pragma("unroll")                                                        \
    for (int j_ = 0; j_ < 2; ++j_)                                           \
      __builtin_amdgcn_global_load_lds(                                      \
        (const AS1 void*)(bSrc + ((h)*128 + j_*64)*(long)K + (long)(kt)*BK), \
        (AS3 void*)((char*)lds + 65536 + (b)*32768 + (h)*16384 + j_*8192 +   \
                    ldsByte), 16,0,0);                                       \
  } while (0)

#define SBAR  __builtin_amdgcn_sched_barrier(0)
#define BAR   __builtin_amdgcn_s_barrier()
#define LGKM0 do { asm volatile("s_waitcnt lgkmcnt(0)" ::: "memory"); SBAR; } while (0)
#define LGKM8 do { asm volatile("s_waitcnt lgkmcnt(8)" ::: "memory"); } while (0)

  // 4 phases computing K-tile in buf B_. TOP: vmcnt(W1) then BARRIER — each
  // wave drains ITS OWN tile loads, rendezvous certifies whole buffer (r6 fix).
  // No closing barrier in ph4 (the next tile's top barrier serves).
#define TILE4(B_, W1, S1, S2, S3, S4) do {                                   \
    asm volatile("s_waitcnt vmcnt(" W1 ")" ::: "memory");                    \
    BAR;                                                                     \
    const unsigned short* Ab_ = lds + (B_)*16384 + fragA;                    \
    const unsigned short* Bb_ = lds + 32768 + (B_)*16384 + fragB;            \
    bf16x8 af_[4][2], bl_[2][2], bh_[2][2], ag_[4][2];                       \
    /* ---- phase 1: 12 ds_read (A-lo, B-lo); stage; q(m0-3,n0-1) ---- */    \
    _Pragma("unroll")                                                        \
    for (int m_ = 0; m_ < 4; ++m_) {                                         \
      af_[m_][0] = *(const bf16x8*)(Ab_ + m_*1024 + kx0);                    \
      af_[m_][1] = *(const bf16x8*)(Ab_ + m_*1024 + kx1); }                  \
    _Pragma("unroll")                                                        \
    for (int n_ = 0; n_ < 2; ++n_) {                                         \
      bl_[n_][0] = *(const bf16x8*)(Bb_ + n_*1024 + kx0);                    \
      bl_[n_][1] = *(const bf16x8*)(Bb_ + n_*1024 + kx1); }                  \
    S1;                                                                      \
    LGKM8;                                                                   \
    SBAR; BAR; LGKM0;                                                        \
    __builtin_amdgcn_s_setprio(1);                                           \
    _Pragma("unroll")                                                        \
    for (int m_ = 0; m_ < 4; ++m_)                                           \
      _Pragma("unroll")                                                      \
      for (int n_ = 0; n_ < 2; ++n_) {                                       \
        acc[m_][n_] = MFMA(af_[m_][0], bl_[n_][0], acc[m_][n_]);             \
        acc[m_][n_] = MFMA(af_[m_][1], bl_[n_][1], acc[m_][n_]); }           \
    __builtin_amdgcn_s_setprio(0);                                           \
    SBAR; BAR;                                                               \
    /* ---- phase 2: 4 ds_read (B-hi); stage; q(m0-3,n2-3) ---- */           \
    _Pragma("unroll")                                                        \
    for (int n_ = 0; n_ < 2; ++n_) {                                         \
      bh_[n_][0] = *(const bf16x8*)(Bb_ + (n_+2)*1024 + kx0);                \
      bh_[n_][1] = *(const bf16x8*)(Bb_ + (n_+2)*1024 + kx1); }              \
    S2;                                                                      \
    SBAR; BAR; LGKM0;                                                        \
    __builtin_amdgcn_s_setprio(1);                                           \
    _Pragma("unroll")                                                        \
    for (int m_ = 0; m_ < 4; ++m_)                                           \
      _Pragma("unroll")                                                      \
      for (int n_ = 0; n_ < 2; ++n_) {                                       \
        acc[m_][n_+2] = MFMA(af_[m_][0], bh_[n_][0], acc[m_][n_+2]);         \
        acc[m_][n_+2] = MFMA(af_[m_][1], bh_[n_][1], acc[m_][n_+2]); }       \
    __builtin_amdgcn_s_setprio(0);                                           \
    SBAR; BAR;                                                               \
    /* ---- phase 3: 8 ds_read (A-hi); stage; q(m4-7,n0-1) ---- */           \
    _Pragma("unroll")                                                        \
    for (int m_ = 0; m_ < 4; ++m_) {                                         \
      ag_[m_][0] = *(const bf16x8*)(Ab_ + (m_+4)*1024 + kx0);                \
      ag_[m_][1] = *(const bf16x8*)(Ab_ + (m_+4)*1024 + kx1); }              \
    S3;                                                                      \
    SBAR; BAR; LGKM0;                                                        \
    __builtin_amdgcn_s_setprio(1);                                           \
    _Pragma("unroll")                                                        \
    for (int m_ = 0; m_ < 4; ++m_)                                           \
      _Pragma("unroll")                                                      \
      for (int n_ = 0; n_ < 2; ++n_) {                                       \
        acc[m_+4][n_] = MFMA(ag_[m_][0], bl_[n_][0], acc[m_+4][n_]);         \
        acc[m_+4][n_] = MFMA(ag_[m_][1], bl_[n_][1], acc[m_+4][n_]); }       \
    __builtin_amdgcn_s_setprio(0);                                           \
    SBAR; BAR;                                                               \
    /* ---- phase 4: 0 ds_read; stage; q(m4-7,n2-3); no closing BAR ---- */  \
    S4;                                                                      \
    SBAR;                                                                    \
    __builtin_amdgcn_s_setprio(1);                                           \
    _Pragma("unroll")                                                        \
    for (int m_ = 0; m_ < 4; ++m_)                                           \
      _Pragma("unroll")                                                      \
      for (int n_ = 0; n_ < 2; ++n_) {                                       \
        acc[m_+4][n_+2] = MFMA(ag_[m_][0], bh_[n_][0], acc[m_+4][n_+2]);     \
        acc[m_+4][n_+2] = MFMA(ag_[m_][1], bh_[n_][1], acc[m_+4][n_+2]); }   \
    __builtin_amdgcn_s_setprio(0);                                           \
    SBAR;                                                                    \
  } while (0)

  // prologue: tile 0 fully + tile 1 halves B0,A0 (12 loads; vmcnt(4) at
  // first ph1 completes exactly tile 0's buffer)
  STGB(0, 0, 0); STGA(0, 0, 0); STGB(0, 1, 0); STGA(0, 1, 0);
  STGB(1, 0, 1); STGA(1, 0, 1);

  // steady state: iter i computes tiles 2i (buf0), 2i+1 (buf1); stages the
  // half-tile rotation (each overwrite lands >=1 closing-barrier after the
  // last read of its region).
  const int npair = nt / 2;
  for (int i = 0; i < npair - 1; ++i) {
    int t2 = 2 * i;
    TILE4(0, "4", STGB(1,1,t2+1), STGA(1,1,t2+1), STGB(0,0,t2+2), STGA(0,0,t2+2));
    TILE4(1, "4", STGB(0,1,t2+2), STGA(0,1,t2+2), STGB(1,0,t2+3), STGA(1,0,t2+3));
  }
  // last pair: only tile nt-1's B1/A1 remain to stage
  TILE4(0, "4", STGB(1,1,nt-1), STGA(1,1,nt-1), , );
  TILE4(1, "0", , , , );

#undef TILE4
#undef STGA
#undef STGB

  // epilogue: C/D layout col = lane&15, row = (lane>>4)*4 + i
  #pragma unroll
  for (int n = 0; n < 4; ++n) {
    long col = n0 + wc * 64 + n * 16 + l15;
    float bv = bias[col];
    #pragma unroll
    for (int m = 0; m < 8; ++m) {
      long row0 = m0 + wr * 128 + m * 16 + (g << 2);
      #pragma unroll
      for (int i = 0; i < 4; ++i)
        out[(row0 + i) * (long)N + col] = acc[m][n][i] + bv;
    }
  }
}

extern "C" void kernel_launch(void* const* d_in, const int* in_sizes, int n_in,
                              void* d_out, int out_size, void* d_ws, size_t ws_size,
                              hipStream_t stream) {
  const float* x    = (const float*)d_in[0];
  const float* W    = (const float*)d_in[1];
  const float* b    = (const float*)d_in[2];
  const float* A    = (const float*)d_in[3];
  const float* Bm   = (const float*)d_in[4];

  const long D_out = in_sizes[2];                 // 4096
  const long D_in  = (long)in_sizes[1] / D_out;   // 4096
  const long M     = (long)in_sizes[0] / D_in;    // 16384
  const int  R     = (int)((long)in_sizes[3] / D_in);  // 16
  const int  K = (int)D_in, N = (int)D_out;

  unsigned short* xb = (unsigned short*)d_ws;
  unsigned short* wt = xb + (size_t)M * K;

  cvt_bf16_kernel<<<2048, 256, 0, stream>>>(x, xb, M * (long)K);
  build_wt_kernel<<<(K >> 6) * (N >> 6), 256, 0, stream>>>(W, A, Bm, wt, K, N, R);

  int grid = (int)((M / BM) * ((long)N / BN));    // 64 * 16 = 1024
  gemm_kernel<<<grid, 512, 128 * 1024, stream>>>(
      xb, wt, b, (float*)d_out, (int)M, N, K);
}